// Round 1
// baseline (1706.509 us; speedup 1.0000x reference)
//
#include <hip/hip_runtime.h>

#define N_IDS 600001

// Scatter-max: for each pair (id0,id1) with value v, max-update two tables.
// Values are uniform[0,1) >= 0, tables init to 0 -> int-compare atomicMax on
// the float bit pattern is exact. Pre-check read is safe: table values are
// monotone non-decreasing, so any stale cached value is a lower bound.
__device__ __forceinline__ void amax(float* __restrict__ tab, int id, float v) {
    float cur = tab[id];
    if (v > cur) {
        atomicMax((int*)(tab + id), __float_as_int(v));
    }
}

__global__ __launch_bounds__(256) void scatter_max_kernel(
    const int4* __restrict__ pp,     // pred_pair viewed as int4: 2 pairs each
    const float4* __restrict__ feat, // 4 values
    float* __restrict__ max0,
    float* __restrict__ max1,
    int n4)                          // n/4 (n is 2^25, divisible)
{
    int i = blockIdx.x * blockDim.x + threadIdx.x;
    if (i >= n4) return;
    int4 a = pp[2 * i];
    int4 b = pp[2 * i + 1];
    float4 f = feat[i];
    amax(max0, a.x, f.x); amax(max1, a.y, f.x);
    amax(max0, a.z, f.y); amax(max1, a.w, f.y);
    amax(max0, b.x, f.z); amax(max1, b.y, f.z);
    amax(max0, b.z, f.w); amax(max1, b.w, f.w);
}

__global__ __launch_bounds__(256) void gather_mul_kernel(
    const int4* __restrict__ pp,
    const float* __restrict__ max0,
    const float* __restrict__ max1,
    float4* __restrict__ out,
    int n4)
{
    int i = blockIdx.x * blockDim.x + threadIdx.x;
    if (i >= n4) return;
    int4 a = pp[2 * i];
    int4 b = pp[2 * i + 1];
    float4 o;
    o.x = max0[a.x] * max1[a.y];
    o.y = max0[a.z] * max1[a.w];
    o.z = max0[b.x] * max1[b.y];
    o.w = max0[b.z] * max1[b.w];
    out[i] = o;
}

// Tail kernel (defensive; n = 2^25 so normally unused).
__global__ void tail_kernel(
    const int* __restrict__ pp,
    const float* __restrict__ feat,
    float* __restrict__ max0,
    float* __restrict__ max1,
    int start, int n)
{
    int i = start + blockIdx.x * blockDim.x + threadIdx.x;
    if (i >= n) return;
    int id0 = pp[2 * i];
    int id1 = pp[2 * i + 1];
    float v = feat[i];
    amax(max0, id0, v);
    amax(max1, id1, v);
}

__global__ void tail_gather_kernel(
    const int* __restrict__ pp,
    const float* __restrict__ max0,
    const float* __restrict__ max1,
    float* __restrict__ out,
    int start, int n)
{
    int i = start + blockIdx.x * blockDim.x + threadIdx.x;
    if (i >= n) return;
    out[i] = max0[pp[2 * i]] * max1[pp[2 * i + 1]];
}

extern "C" void kernel_launch(void* const* d_in, const int* in_sizes, int n_in,
                              void* d_out, int out_size, void* d_ws, size_t ws_size,
                              hipStream_t stream) {
    const int*   pp   = (const int*)d_in[0];    // (n,2) int32, interleaved
    const float* feat = (const float*)d_in[1];  // (n,) float32
    float* out = (float*)d_out;

    int n = in_sizes[1];

    float* max0 = (float*)d_ws;
    float* max1 = max0 + N_IDS;

    // Tables must be zero (reg_feat >= 0, so 0 is the identity as in the ref).
    hipMemsetAsync(d_ws, 0, 2 * (size_t)N_IDS * sizeof(float), stream);

    int n4 = n / 4;
    int tail_start = n4 * 4;
    dim3 block(256);
    dim3 grid((n4 + 255) / 256);

    scatter_max_kernel<<<grid, block, 0, stream>>>(
        (const int4*)pp, (const float4*)feat, max0, max1, n4);
    if (tail_start < n) {
        int t = n - tail_start;
        tail_kernel<<<(t + 255) / 256, 256, 0, stream>>>(
            pp, feat, max0, max1, tail_start, n);
    }
    gather_mul_kernel<<<grid, block, 0, stream>>>(
        (const int4*)pp, max0, max1, (float4*)out, n4);
    if (tail_start < n) {
        int t = n - tail_start;
        tail_gather_kernel<<<(t + 255) / 256, 256, 0, stream>>>(
            pp, max0, max1, out, tail_start, n);
    }
}

// Round 2
// 1005.049 us; speedup vs baseline: 1.6979x; 1.6979x over previous
//
#include <hip/hip_runtime.h>
#include <hip/hip_fp16.h>

#define N_IDS 600001
#define TAB_STRIDE 600016          // 16-aligned element stride for tables
#define TAU 0.90f
#define BM_WORDS 9376              // ceil(ceil(600001/2)/32): 1 bit covers 2 bins

// float atomic max via int compare: valid because all values >= 0 and table
// initialized to 0 (IEEE non-negative floats order like their int bits).
__device__ __forceinline__ void amax_atomic(float* __restrict__ tab, int id, float v) {
    atomicMax((int*)(tab + id), __float_as_int(v));
}

// ---------------- Pass A: atomics only for v >= tau (~10% of updates) -------
__global__ __launch_bounds__(256) void pass_a_kernel(
    const int4* __restrict__ pp, const float4* __restrict__ feat,
    float* __restrict__ t0, float* __restrict__ t1, float tau, int n4)
{
    int i = blockIdx.x * blockDim.x + threadIdx.x;
    if (i >= n4) return;
    float4 f = feat[i];
    float m = fmaxf(fmaxf(f.x, f.y), fmaxf(f.z, f.w));
    if (m < tau) return;                       // skip pp load for ~66% of threads
    int4 a = pp[2 * i];
    int4 b = pp[2 * i + 1];
    if (f.x >= tau) { amax_atomic(t0, a.x, f.x); amax_atomic(t1, a.y, f.x); }
    if (f.y >= tau) { amax_atomic(t0, a.z, f.y); amax_atomic(t1, a.w, f.y); }
    if (f.z >= tau) { amax_atomic(t0, b.x, f.z); amax_atomic(t1, b.y, f.z); }
    if (f.w >= tau) { amax_atomic(t0, b.z, f.w); amax_atomic(t1, b.w, f.w); }
}

// ---------------- Bitmap: bit = any of 4 covered entries still < tau --------
__global__ void bitmap_kernel(const float* __restrict__ t0,
                              const float* __restrict__ t1,
                              unsigned* __restrict__ bm)
{
    int w = blockIdx.x * blockDim.x + threadIdx.x;
    if (w >= BM_WORDS) return;
    unsigned word = 0;
    int base = w * 64;                         // first bin covered by this word
    for (int b = 0; b < 32; ++b) {
        int i0 = base + 2 * b;
        bool open = false;
        #pragma unroll
        for (int k = 0; k < 2; ++k) {
            int id = i0 + k;
            if (id < N_IDS) open = open || (t0[id] < TAU) || (t1[id] < TAU);
        }
        if (open) word |= (1u << b);
    }
    bm[w] = word;
}

// ---------------- Pass B: LDS bitmap filter, atomic only for open bins ------
__device__ __forceinline__ bool open_bit(const unsigned* lbm, int id) {
    int bi = id >> 1;
    return (lbm[bi >> 5] >> (bi & 31)) & 1u;
}

__device__ __forceinline__ void pb_update(const unsigned* lbm,
                                          float* __restrict__ t0,
                                          float* __restrict__ t1,
                                          int id0, int id1, float v)
{
    if (v < TAU) {                              // v >= TAU handled by pass A
        if (open_bit(lbm, id0)) amax_atomic(t0, id0, v);
        if (open_bit(lbm, id1)) amax_atomic(t1, id1, v);
    }
}

__global__ __launch_bounds__(256) void pass_b_kernel(
    const int4* __restrict__ pp, const float4* __restrict__ feat,
    float* __restrict__ t0, float* __restrict__ t1,
    const unsigned* __restrict__ bm, int n4)
{
    __shared__ unsigned lbm[BM_WORDS];          // 37.5 KB -> 4 blocks/CU
    for (int w = threadIdx.x; w < BM_WORDS; w += 256) lbm[w] = bm[w];
    __syncthreads();
    int stride = gridDim.x * blockDim.x;
    for (int i = blockIdx.x * blockDim.x + threadIdx.x; i < n4; i += stride) {
        float4 f = feat[i];
        float mn = fminf(fminf(f.x, f.y), fminf(f.z, f.w));
        if (mn >= TAU) continue;                // all 4 already done in pass A
        int4 a = pp[2 * i];
        int4 b = pp[2 * i + 1];
        pb_update(lbm, t0, t1, a.x, a.y, f.x);
        pb_update(lbm, t0, t1, a.z, a.w, f.y);
        pb_update(lbm, t0, t1, b.x, b.y, f.z);
        pb_update(lbm, t0, t1, b.z, b.w, f.w);
    }
}

// ---------------- Pack tables to fp16 (both then fit one XCD L2) ------------
__global__ void pack_kernel(const float* __restrict__ t0,
                            const float* __restrict__ t1,
                            __half* __restrict__ h0, __half* __restrict__ h1)
{
    int i = blockIdx.x * blockDim.x + threadIdx.x;
    if (i < N_IDS) {
        h0[i] = __float2half_rn(t0[i]);
        h1[i] = __float2half_rn(t1[i]);
    }
}

// ---------------- Gather ---------------------------------------------------
__global__ __launch_bounds__(256) void gather_h_kernel(
    const int4* __restrict__ pp, const __half* __restrict__ h0,
    const __half* __restrict__ h1, float4* __restrict__ out, int n4)
{
    int i = blockIdx.x * blockDim.x + threadIdx.x;
    if (i >= n4) return;
    int4 a = pp[2 * i];
    int4 b = pp[2 * i + 1];
    float4 o;
    o.x = __half2float(h0[a.x]) * __half2float(h1[a.y]);
    o.y = __half2float(h0[a.z]) * __half2float(h1[a.w]);
    o.z = __half2float(h0[b.x]) * __half2float(h1[b.y]);
    o.w = __half2float(h0[b.z]) * __half2float(h1[b.w]);
    out[i] = o;
}

__global__ __launch_bounds__(256) void gather_f_kernel(
    const int4* __restrict__ pp, const float* __restrict__ t0,
    const float* __restrict__ t1, float4* __restrict__ out, int n4)
{
    int i = blockIdx.x * blockDim.x + threadIdx.x;
    if (i >= n4) return;
    int4 a = pp[2 * i];
    int4 b = pp[2 * i + 1];
    float4 o;
    o.x = t0[a.x] * t1[a.y];
    o.y = t0[a.z] * t1[a.w];
    o.z = t0[b.x] * t1[b.y];
    o.w = t0[b.z] * t1[b.w];
    out[i] = o;
}

// ---------------- Defensive scalar tails (n = 2^25, normally unused) --------
__global__ void tail_scatter_kernel(const int* __restrict__ pp,
                                    const float* __restrict__ feat,
                                    float* __restrict__ t0, float* __restrict__ t1,
                                    int start, int n)
{
    int i = start + blockIdx.x * blockDim.x + threadIdx.x;
    if (i >= n) return;
    float v = feat[i];
    amax_atomic(t0, pp[2 * i], v);
    amax_atomic(t1, pp[2 * i + 1], v);
}

__global__ void tail_gather_h_kernel(const int* __restrict__ pp,
                                     const __half* __restrict__ h0,
                                     const __half* __restrict__ h1,
                                     float* __restrict__ out, int start, int n)
{
    int i = start + blockIdx.x * blockDim.x + threadIdx.x;
    if (i >= n) return;
    out[i] = __half2float(h0[pp[2 * i]]) * __half2float(h1[pp[2 * i + 1]]);
}

__global__ void tail_gather_f_kernel(const int* __restrict__ pp,
                                     const float* __restrict__ t0,
                                     const float* __restrict__ t1,
                                     float* __restrict__ out, int start, int n)
{
    int i = start + blockIdx.x * blockDim.x + threadIdx.x;
    if (i >= n) return;
    out[i] = t0[pp[2 * i]] * t1[pp[2 * i + 1]];
}

extern "C" void kernel_launch(void* const* d_in, const int* in_sizes, int n_in,
                              void* d_out, int out_size, void* d_ws, size_t ws_size,
                              hipStream_t stream) {
    const int*   pp   = (const int*)d_in[0];    // (n,2) int32, interleaved
    const float* feat = (const float*)d_in[1];  // (n,) float32
    float* out = (float*)d_out;
    int n = in_sizes[1];

    // Workspace layout:
    //   [t0: TAB_STRIDE f32][t1: TAB_STRIDE f32][bitmap: BM_WORDS u32 ...
    //    ... overlaid/followed by h0,h1 fp16 tables]
    float* t0 = (float*)d_ws;
    float* t1 = t0 + TAB_STRIDE;
    size_t tab_bytes = 2 * (size_t)TAB_STRIDE * sizeof(float);     // 4,800,128
    unsigned* bm = (unsigned*)((char*)d_ws + tab_bytes);
    // fp16 tables placed after the bitmap (no overlap; bitmap stays valid)
    __half* h0 = (__half*)((char*)d_ws + tab_bytes + BM_WORDS * sizeof(unsigned));
    __half* h1 = h0 + TAB_STRIDE;

    size_t need_bitmap = tab_bytes + BM_WORDS * sizeof(unsigned);
    size_t need_fp16   = need_bitmap + 2 * (size_t)TAB_STRIDE * sizeof(__half);
    bool use_bitmap = ws_size >= need_bitmap;   // filtered scatter path
    bool use_fp16   = ws_size >= need_fp16;     // fp16 gather path

    hipMemsetAsync(d_ws, 0, tab_bytes, stream); // tables must start at 0

    int n4 = n / 4;
    int tail_start = n4 * 4;
    dim3 block(256);
    dim3 grid((n4 + 255) / 256);

    if (use_bitmap) {
        // Pass A: only v >= TAU issues atomics (~10% of updates)
        pass_a_kernel<<<grid, block, 0, stream>>>(
            (const int4*)pp, (const float4*)feat, t0, t1, TAU, n4);
        // Bitmap of still-open bins (table entry < TAU)
        bitmap_kernel<<<(BM_WORDS + 255) / 256, 256, 0, stream>>>(t0, t1, bm);
        // Pass B: LDS-bitmap-filtered atomics for v < TAU (~1-2% issue)
        pass_b_kernel<<<1024, block, 0, stream>>>(
            (const int4*)pp, (const float4*)feat, t0, t1, bm, n4);
    } else {
        // Fallback: unfiltered scatter (tau = -1 -> every update fires)
        pass_a_kernel<<<grid, block, 0, stream>>>(
            (const int4*)pp, (const float4*)feat, t0, t1, -1.0f, n4);
    }
    if (tail_start < n) {
        int t = n - tail_start;
        tail_scatter_kernel<<<(t + 255) / 256, 256, 0, stream>>>(
            pp, feat, t0, t1, tail_start, n);
    }

    if (use_fp16) {
        pack_kernel<<<(N_IDS + 255) / 256, 256, 0, stream>>>(t0, t1, h0, h1);
        gather_h_kernel<<<grid, block, 0, stream>>>(
            (const int4*)pp, h0, h1, (float4*)out, n4);
        if (tail_start < n) {
            int t = n - tail_start;
            tail_gather_h_kernel<<<(t + 255) / 256, 256, 0, stream>>>(
                pp, h0, h1, out, tail_start, n);
        }
    } else {
        gather_f_kernel<<<grid, block, 0, stream>>>(
            (const int4*)pp, t0, t1, (float4*)out, n4);
        if (tail_start < n) {
            int t = n - tail_start;
            tail_gather_f_kernel<<<(t + 255) / 256, 256, 0, stream>>>(
                pp, t0, t1, out, tail_start, n);
        }
    }
}

// Round 4
// 1003.386 us; speedup vs baseline: 1.7008x; 1.0017x over previous
//
#include <hip/hip_runtime.h>
#include <hip/hip_fp16.h>

#define N_IDS      600001
#define TAB_STRIDE 600016          // padded element stride
#define TAU        0.90f
#define BM_WORDS   9376            // ceil(ceil(600001/2)/32): 1 bit per bin-pair

// Native clang vector types (accepted by __builtin_nontemporal_*)
typedef int   v4i __attribute__((ext_vector_type(4)));
typedef float v4f __attribute__((ext_vector_type(4)));

// Interleaved table: tt[2*id] = t0[id], tt[2*id+1] = t1[id].
// Float atomic-max via int compare: valid (all values >= 0, init 0).
__device__ __forceinline__ void amax0(float* __restrict__ tt, int id, float v) {
    atomicMax((int*)(tt + 2 * id), __float_as_int(v));
}
__device__ __forceinline__ void amax1(float* __restrict__ tt, int id, float v) {
    atomicMax((int*)(tt + 2 * id + 1), __float_as_int(v));
}

// ---------------- Pass A: atomics only for v >= tau, 8 elems/thread ---------
__global__ __launch_bounds__(256) void pass_a_kernel(
    const v4i* __restrict__ pp4, const v4f* __restrict__ feat4,
    float* __restrict__ tt, float tau, int n8)
{
    int j = blockIdx.x * blockDim.x + threadIdx.x;
    if (j >= n8) return;
    v4f f0 = feat4[2 * j];
    v4f f1 = feat4[2 * j + 1];
    float m0 = fmaxf(fmaxf(f0.x, f0.y), fmaxf(f0.z, f0.w));
    float m1 = fmaxf(fmaxf(f1.x, f1.y), fmaxf(f1.z, f1.w));
    if (m0 < tau && m1 < tau) return;
    if (m0 >= tau) {
        v4i a = pp4[4 * j];
        v4i b = pp4[4 * j + 1];
        if (f0.x >= tau) { amax0(tt, a.x, f0.x); amax1(tt, a.y, f0.x); }
        if (f0.y >= tau) { amax0(tt, a.z, f0.y); amax1(tt, a.w, f0.y); }
        if (f0.z >= tau) { amax0(tt, b.x, f0.z); amax1(tt, b.y, f0.z); }
        if (f0.w >= tau) { amax0(tt, b.z, f0.w); amax1(tt, b.w, f0.w); }
    }
    if (m1 >= tau) {
        v4i c = pp4[4 * j + 2];
        v4i d = pp4[4 * j + 3];
        if (f1.x >= tau) { amax0(tt, c.x, f1.x); amax1(tt, c.y, f1.x); }
        if (f1.y >= tau) { amax0(tt, c.z, f1.y); amax1(tt, c.w, f1.y); }
        if (f1.z >= tau) { amax0(tt, d.x, f1.z); amax1(tt, d.y, f1.z); }
        if (f1.w >= tau) { amax0(tt, d.z, f1.w); amax1(tt, d.w, f1.w); }
    }
}

// ---------------- Bitmap: ballot, 1 thread per bin-pair ---------------------
__global__ __launch_bounds__(256) void bitmap_kernel(
    const float* __restrict__ tt, unsigned* __restrict__ bm)
{
    int p = blockIdx.x * blockDim.x + threadIdx.x;   // pair index (bins 2p,2p+1)
    bool open = false;
    if (p < BM_WORDS * 32) {
        // 4 contiguous entries: t0[2p], t1[2p], t0[2p+1], t1[2p+1]
        const v4f e = *(const v4f*)(tt + 4 * (size_t)p);
        open = (e.x < TAU) || (e.y < TAU) || (e.z < TAU) || (e.w < TAU);
    }
    unsigned long long m = __ballot(open);
    int lane = p & 63;
    if (lane == 0)  bm[p >> 5] = (unsigned)m;
    if (lane == 32) bm[p >> 5] = (unsigned)(m >> 32);
}

// ---------------- Pass B: LDS-bitmap filtered, 16 elems/iter ----------------
__device__ __forceinline__ bool open_bit(const unsigned* lbm, int id) {
    int bi = id >> 1;
    return (lbm[bi >> 5] >> (bi & 31)) & 1u;
}

__device__ __forceinline__ void pb_upd(const unsigned* lbm, float* __restrict__ tt,
                                       int id0, int id1, float v)
{
    if (v < TAU) {                      // v >= TAU fully handled by pass A
        if (open_bit(lbm, id0)) amax0(tt, id0, v);
        if (open_bit(lbm, id1)) amax1(tt, id1, v);
    }
}

__global__ __launch_bounds__(256) void pass_b_kernel(
    const v4i* __restrict__ pp4, const v4f* __restrict__ feat4,
    float* __restrict__ tt, const unsigned* __restrict__ bm, int n16)
{
    __shared__ unsigned lbm[BM_WORDS];  // 37.5 KB -> 4 blocks/CU
    for (int w = threadIdx.x; w < BM_WORDS; w += 256) lbm[w] = bm[w];
    __syncthreads();
    int stride = gridDim.x * blockDim.x;
    for (int g = blockIdx.x * blockDim.x + threadIdx.x; g < n16; g += stride) {
        // Issue all 12 loads up front (independent -> max MLP)
        v4f f0 = feat4[4 * g];
        v4f f1 = feat4[4 * g + 1];
        v4f f2 = feat4[4 * g + 2];
        v4f f3 = feat4[4 * g + 3];
        v4i p0 = pp4[8 * g];
        v4i p1 = pp4[8 * g + 1];
        v4i p2 = pp4[8 * g + 2];
        v4i p3 = pp4[8 * g + 3];
        v4i p4 = pp4[8 * g + 4];
        v4i p5 = pp4[8 * g + 5];
        v4i p6 = pp4[8 * g + 6];
        v4i p7 = pp4[8 * g + 7];
        pb_upd(lbm, tt, p0.x, p0.y, f0.x); pb_upd(lbm, tt, p0.z, p0.w, f0.y);
        pb_upd(lbm, tt, p1.x, p1.y, f0.z); pb_upd(lbm, tt, p1.z, p1.w, f0.w);
        pb_upd(lbm, tt, p2.x, p2.y, f1.x); pb_upd(lbm, tt, p2.z, p2.w, f1.y);
        pb_upd(lbm, tt, p3.x, p3.y, f1.z); pb_upd(lbm, tt, p3.z, p3.w, f1.w);
        pb_upd(lbm, tt, p4.x, p4.y, f2.x); pb_upd(lbm, tt, p4.z, p4.w, f2.y);
        pb_upd(lbm, tt, p5.x, p5.y, f2.z); pb_upd(lbm, tt, p5.z, p5.w, f2.w);
        pb_upd(lbm, tt, p6.x, p6.y, f3.x); pb_upd(lbm, tt, p6.z, p6.w, f3.y);
        pb_upd(lbm, tt, p7.x, p7.y, f3.z); pb_upd(lbm, tt, p7.z, p7.w, f3.w);
    }
}

// ---------------- Pack interleaved fp32 table to half2 ---------------------
__global__ __launch_bounds__(256) void pack_kernel(
    const float* __restrict__ tt, __half2* __restrict__ hh)
{
    int i = blockIdx.x * blockDim.x + threadIdx.x;
    if (i < N_IDS) {
        const float* e = tt + 2 * (size_t)i;
        hh[i] = __floats2half2_rn(e[0], e[1]);   // (t0[i], t1[i])
    }
}

// ---------------- Gather: 8 elems/thread, 16 gathers in flight --------------
__global__ __launch_bounds__(256) void gather_kernel(
    const v4i* __restrict__ pp4, const __half2* __restrict__ hh,
    v4f* __restrict__ out4, int n8)
{
    int j = blockIdx.x * blockDim.x + threadIdx.x;
    if (j >= n8) return;
    v4i a = __builtin_nontemporal_load(&pp4[4 * j]);
    v4i b = __builtin_nontemporal_load(&pp4[4 * j + 1]);
    v4i c = __builtin_nontemporal_load(&pp4[4 * j + 2]);
    v4i d = __builtin_nontemporal_load(&pp4[4 * j + 3]);
    __half2 g0 = hh[a.x], g1 = hh[a.y], g2 = hh[a.z], g3 = hh[a.w];
    __half2 g4 = hh[b.x], g5 = hh[b.y], g6 = hh[b.z], g7 = hh[b.w];
    __half2 g8 = hh[c.x], g9 = hh[c.y], ga = hh[c.z], gb = hh[c.w];
    __half2 gc = hh[d.x], gd = hh[d.y], ge = hh[d.z], gf = hh[d.w];
    v4f o0, o1;
    o0.x = __half2float(__low2half(g0)) * __half2float(__high2half(g1));
    o0.y = __half2float(__low2half(g2)) * __half2float(__high2half(g3));
    o0.z = __half2float(__low2half(g4)) * __half2float(__high2half(g5));
    o0.w = __half2float(__low2half(g6)) * __half2float(__high2half(g7));
    o1.x = __half2float(__low2half(g8)) * __half2float(__high2half(g9));
    o1.y = __half2float(__low2half(ga)) * __half2float(__high2half(gb));
    o1.z = __half2float(__low2half(gc)) * __half2float(__high2half(gd));
    o1.w = __half2float(__low2half(ge)) * __half2float(__high2half(gf));
    __builtin_nontemporal_store(o0, &out4[2 * j]);
    __builtin_nontemporal_store(o1, &out4[2 * j + 1]);
}

// ---------------- Defensive scalar tails (n = 2^25 -> unused) ---------------
__global__ void tail_scatter_kernel(const int* __restrict__ pp,
                                    const float* __restrict__ feat,
                                    float* __restrict__ tt, int start, int n)
{
    int i = start + blockIdx.x * blockDim.x + threadIdx.x;
    if (i >= n) return;
    float v = feat[i];
    amax0(tt, pp[2 * i], v);
    amax1(tt, pp[2 * i + 1], v);
}

__global__ void tail_gather_kernel(const int* __restrict__ pp,
                                   const __half2* __restrict__ hh,
                                   float* __restrict__ out, int start, int n)
{
    int i = start + blockIdx.x * blockDim.x + threadIdx.x;
    if (i >= n) return;
    out[i] = __half2float(__low2half(hh[pp[2 * i]])) *
             __half2float(__high2half(hh[pp[2 * i + 1]]));
}

extern "C" void kernel_launch(void* const* d_in, const int* in_sizes, int n_in,
                              void* d_out, int out_size, void* d_ws, size_t ws_size,
                              hipStream_t stream) {
    const int*   pp   = (const int*)d_in[0];    // (n,2) int32, interleaved
    const float* feat = (const float*)d_in[1];  // (n,) float32
    float* out = (float*)d_out;
    int n = in_sizes[1];

    // ws layout: [tt: 2*TAB_STRIDE f32][bm: BM_WORDS u32][hh: TAB_STRIDE half2]
    float* tt = (float*)d_ws;
    size_t tt_bytes = 2 * (size_t)TAB_STRIDE * sizeof(float);      // 4,800,128
    unsigned* bm = (unsigned*)((char*)d_ws + tt_bytes);
    __half2* hh = (__half2*)((char*)d_ws + tt_bytes + BM_WORDS * sizeof(unsigned));

    (void)hipMemsetAsync(d_ws, 0, tt_bytes, stream);  // tables start at 0

    int n8 = n / 8;
    int n16 = n / 16;
    int tail_start = n8 * 8;
    dim3 block(256);
    dim3 gridA((n8 + 255) / 256);

    // Pass A: only v >= TAU issues atomics (~10% of updates)
    pass_a_kernel<<<gridA, block, 0, stream>>>(
        (const v4i*)pp, (const v4f*)feat, tt, TAU, n8);
    if (tail_start < n) {
        int t = n - tail_start;
        tail_scatter_kernel<<<(t + 255) / 256, 256, 0, stream>>>(
            pp, feat, tt, tail_start, n);
    }
    // Bitmap of still-open bin-pairs
    bitmap_kernel<<<(BM_WORDS * 32 + 255) / 256, 256, 0, stream>>>(tt, bm);
    // Pass B: LDS-bitmap-filtered atomics for v < TAU (~1-2% issue)
    pass_b_kernel<<<1024, block, 0, stream>>>(
        (const v4i*)pp, (const v4f*)feat, tt, bm, n16);
    // Pack to half2 and gather
    pack_kernel<<<(N_IDS + 255) / 256, 256, 0, stream>>>(tt, hh);
    gather_kernel<<<gridA, block, 0, stream>>>(
        (const v4i*)pp, hh, (v4f*)out, n8);
    if (tail_start < n) {
        int t = n - tail_start;
        tail_gather_kernel<<<(t + 255) / 256, 256, 0, stream>>>(
            pp, hh, out, tail_start, n);
    }
}